// Round 1
// baseline (3428.806 us; speedup 1.0000x reference)
//
#include <hip/hip_runtime.h>
#include <hip/hip_bf16.h>
#include <hip/hip_fp16.h>

// LSTMDecoder: B=32768, LATENT=32, HID=128, NVAR=9, NSCEN=4, NLAYERS=2, T=60
// Design: persistent block per 128 batch rows; gates-transposed MFMA (Gt = W @ X^T)
// with W rows permuted u' = hid*4 + gate so each lane owns full (i,f,g,o) quads.
// f16 MFMA operands (fp32 accum), c-state in registers, h-state in swizzled LDS.

#define HID   128
#define TSTEP 60
#define CS    488          // LDS X row stride (elems); 244 dw % 32 == 20 (odd*4)
#define K0    272          // Wp0/Wp1/Wop row stride (17 k-tiles of 16)
#define KI    176          // Wpi row stride (11 k-tiles)
#define N0    (512*272)
#define NI    (512*176)
#define NO    (32*272)

typedef _Float16 f16x8 __attribute__((ext_vector_type(8)));
typedef float    f32x16 __attribute__((ext_vector_type(16)));

__device__ __forceinline__ float sigm(float x) {
    float e = __builtin_amdgcn_exp2f(x * -1.4426950408889634f);
    return __builtin_amdgcn_rcpf(1.0f + e);
}
__device__ __forceinline__ float tanh_(float x) {
    float e = __builtin_amdgcn_exp2f(x * -2.8853900817779268f);
    return __builtin_amdgcn_rcpf(1.0f + e) * 2.0f - 1.0f;
}

// ---------------- prep: permute + f16-convert weights into workspace ----------------
// Wp0[u'][k]: u'=h*4+g (g=0..3 -> i,f,g,o ; orig row r=g*128+h)
//   k 0..8   = W_ih0[r][0..8]        (prev part, X cols 0..8)
//   k 9      = b_ih0[r]+b_hh0[r]     (bias; X col 9 == 1.0)
//   k 16..143= W_ih0[r][9..136]      (se part,  X cols 16..143)
//   k144..271= W_hh0[r][0..127]      (h0 part,  X cols 144..271)
// Wp1[u'][k]: k0..127=W_ih1 (h0n), k128..255=W_hh1 (h1), k256=bias (X col 400)
// Wpi[u'][k]: u'=h*4+q (q=0:h0,1:c0,2:h1,3:c1; orig row r=q*128+h)
//   k0..127=W_init[r][32..159] (se), k128..159=W_init[r][0..31] (z @ X col 144..175),
//   k160=b_init[r] (X col 176 == 1.0)
// Wop[v][k]: v<9: k128..255=W_out[v][:], k256=b_out[v]; else 0
__global__ void prep_kernel(const float* __restrict__ Winit, const float* __restrict__ binit,
                            const float* __restrict__ Wih0, const float* __restrict__ Whh0,
                            const float* __restrict__ bih0, const float* __restrict__ bhh0,
                            const float* __restrict__ Wih1, const float* __restrict__ Whh1,
                            const float* __restrict__ bih1, const float* __restrict__ bhh1,
                            const float* __restrict__ Wout, const float* __restrict__ bout,
                            _Float16* __restrict__ ws)
{
    int i = blockIdx.x * 256 + threadIdx.x;
    _Float16* Wp0 = ws;
    _Float16* Wp1 = ws + N0;
    _Float16* Wpi = ws + 2 * N0;
    _Float16* Wop = ws + 2 * N0 + NI;

    if (i < N0) {
        int u = i / K0, k = i - u * K0;
        int g = u & 3, h = u >> 2, r = g * 128 + h;
        float v0 = 0.0f;
        if (k < 9)                 v0 = Wih0[r * 137 + k];
        else if (k == 9)           v0 = bih0[r] + bhh0[r];
        else if (k >= 16 && k < 144) v0 = Wih0[r * 137 + 9 + (k - 16)];
        else if (k >= 144)         v0 = Whh0[r * 128 + (k - 144)];
        Wp0[i] = (_Float16)v0;
        float v1 = 0.0f;
        if (k < 128)               v1 = Wih1[r * 128 + k];
        else if (k < 256)          v1 = Whh1[r * 128 + (k - 128)];
        else if (k == 256)         v1 = bih1[r] + bhh1[r];
        Wp1[i] = (_Float16)v1;
    }
    if (i < NI) {
        int u = i / KI, k = i - u * KI;
        int q = u & 3, h = u >> 2, r = q * 128 + h;
        float v = 0.0f;
        if (k < 128)       v = Winit[r * 160 + 32 + k];
        else if (k < 160)  v = Winit[r * 160 + (k - 128)];
        else if (k == 160) v = binit[r];
        Wpi[i] = (_Float16)v;
    }
    if (i < NO) {
        int vv = i / K0, k = i - vv * K0;
        float v = 0.0f;
        if (vv < 9) {
            if (k >= 128 && k < 256) v = Wout[vv * 128 + (k - 128)];
            else if (k == 256)       v = bout[vv];
        }
        Wop[i] = (_Float16)v;
    }
}

// ---------------- main persistent kernel ----------------
__global__ __launch_bounds__(512, 2) void lstm_main(
    const float* __restrict__ z, const int* __restrict__ scen,
    const float* __restrict__ emb, const _Float16* __restrict__ ws,
    float* __restrict__ out)
{
    __shared__ _Float16 Xs[128 * CS];

    const int tid = threadIdx.x;
    const int w  = tid >> 6;        // wave 0..7
    const int l  = tid & 63;
    const int hi = l >> 5;          // k-group half
    const int ln = l & 31;
    const int hi8 = hi * 8;
    const int Bb = blockIdx.x * 128;

    const _Float16* Wp0 = ws;
    const _Float16* Wp1 = ws + N0;
    const _Float16* Wpi = ws + 2 * N0;
    const _Float16* Wop = ws + 2 * N0 + NI;

    // swizzle: phys col = col ^ (((b>>1)&7)<<3)  (XOR on 16B-group bits, keeps 16B units)
    // per-ct batch row/base/key
    int xb[4], xk[4];
#pragma unroll
    for (int ct = 0; ct < 4; ct++) {
        int b = ct * 32 + ln;
        xb[ct] = b * CS;
        xk[ct] = ((b >> 1) & 7) << 3;
    }

    // ---- zero LDS ----
    for (int i = tid; i < 128 * CS; i += 512) Xs[i] = (_Float16)0.0f;
    __syncthreads();

    // ---- load se, z, bias-ones ----
    for (int i = tid; i < 128 * HID; i += 512) {
        int b = i >> 7, j = i & 127;
        int sc = scen[Bb + b];
        int key = ((b >> 1) & 7) << 3;
        Xs[b * CS + ((16 + j) ^ key)] = (_Float16)emb[sc * 128 + j];
    }
    for (int i = tid; i < 128 * 32; i += 512) {
        int b = i >> 5, j = i & 31;
        int key = ((b >> 1) & 7) << 3;
        Xs[b * CS + ((144 + j) ^ key)] = (_Float16)z[(Bb + b) * 32 + j];
    }
    for (int b = tid; b < 128; b += 512) {
        int key = ((b >> 1) & 7) << 3;
        Xs[b * CS + (9 ^ key)]   = (_Float16)1.0f;  // bias col for G0
        Xs[b * CS + (176 ^ key)] = (_Float16)1.0f;  // bias col for init
        Xs[b * CS + (400 ^ key)] = (_Float16)1.0f;  // bias col for G1 / out
    }
    __syncthreads();

    float c0r[2][4][4], c1r[2][4][4];   // [rt][rg][ct]

    const int ra0 = (w * 64 + ln) * K0 + hi8;
    const int ra1 = (w * 64 + 32 + ln) * K0 + hi8;

    // ---- init GEMM: h_init = [se|z|1] @ Wpi^T ; rows u'=h*4+q ----
    {
        const int ri0 = (w * 64 + ln) * KI + hi8;
        const int ri1 = (w * 64 + 32 + ln) * KI + hi8;
        f32x16 acc[2][4] = {};
        for (int kt = 0; kt < 11; kt++) {
            f16x8 a0 = *(const f16x8*)(Wpi + ri0 + kt * 16);
            f16x8 a1 = *(const f16x8*)(Wpi + ri1 + kt * 16);
            const int col = 16 + kt * 16 + hi8;
#pragma unroll
            for (int ct = 0; ct < 4; ct++) {
                f16x8 bv = *(const f16x8*)(Xs + xb[ct] + (col ^ xk[ct]));
                acc[0][ct] = __builtin_amdgcn_mfma_f32_32x32x16_f16(a0, bv, acc[0][ct], 0, 0, 0);
                acc[1][ct] = __builtin_amdgcn_mfma_f32_32x32x16_f16(a1, bv, acc[1][ct], 0, 0, 0);
            }
        }
        __syncthreads();   // all reads of z region done before h0 overwrite
#pragma unroll
        for (int rt = 0; rt < 2; rt++)
#pragma unroll
        for (int ct = 0; ct < 4; ct++) {
#pragma unroll
            for (int rg = 0; rg < 4; rg++) {
                int hid = (w << 4) + rt * 8 + 2 * rg + hi;
                float vh0 = acc[rt][ct][4 * rg + 0];
                float vc0 = acc[rt][ct][4 * rg + 1];
                float vh1 = acc[rt][ct][4 * rg + 2];
                float vc1 = acc[rt][ct][4 * rg + 3];
                c0r[rt][rg][ct] = vc0;
                c1r[rt][rg][ct] = vc1;
                Xs[xb[ct] + ((144 + hid) ^ xk[ct])] = (_Float16)vh0;
                Xs[xb[ct] + ((272 + hid) ^ xk[ct])] = (_Float16)vh1;
            }
        }
    }
    __syncthreads();

    // ---- time loop ----
#pragma unroll 1
    for (int t = 0; t < TSTEP; t++) {
        // ===== G0: gates0 = Wp0 @ [prev|1|se|h0]^T =====
        f32x16 acc[2][4] = {};
        {
            f16x8 a0 = *(const f16x8*)(Wp0 + ra0);
            f16x8 a1 = *(const f16x8*)(Wp0 + ra1);
#pragma unroll 1
            for (int kt = 0; kt < 17; kt++) {
                f16x8 ca = a0, cb = a1;
                if (kt < 16) {
                    a0 = *(const f16x8*)(Wp0 + ra0 + (kt + 1) * 16);
                    a1 = *(const f16x8*)(Wp0 + ra1 + (kt + 1) * 16);
                }
                const int col = kt * 16 + hi8;
#pragma unroll
                for (int ct = 0; ct < 4; ct++) {
                    f16x8 bv = *(const f16x8*)(Xs + xb[ct] + (col ^ xk[ct]));
                    acc[0][ct] = __builtin_amdgcn_mfma_f32_32x32x16_f16(ca, bv, acc[0][ct], 0, 0, 0);
                    acc[1][ct] = __builtin_amdgcn_mfma_f32_32x32x16_f16(cb, bv, acc[1][ct], 0, 0, 0);
                }
            }
        }
        __syncthreads();   // G0 readers done before h0 overwrite

        // ===== E0: layer-0 cell update, write h0n =====
#pragma unroll
        for (int rt = 0; rt < 2; rt++)
#pragma unroll
        for (int ct = 0; ct < 4; ct++) {
#pragma unroll
            for (int rg = 0; rg < 4; rg++) {
                float gi = acc[rt][ct][4 * rg + 0];
                float gf = acc[rt][ct][4 * rg + 1];
                float gg = acc[rt][ct][4 * rg + 2];
                float go = acc[rt][ct][4 * rg + 3];
                float c = sigm(gf) * c0r[rt][rg][ct] + sigm(gi) * tanh_(gg);
                c0r[rt][rg][ct] = c;
                float h = sigm(go) * tanh_(c);
                int hid = (w << 4) + rt * 8 + 2 * rg + hi;
                Xs[xb[ct] + ((144 + hid) ^ xk[ct])] = (_Float16)h;
            }
        }
        __syncthreads();   // h0n visible

        // ===== G1: gates1 = Wp1 @ [h0n|h1|1]^T =====
#pragma unroll
        for (int rt = 0; rt < 2; rt++)
#pragma unroll
        for (int ct = 0; ct < 4; ct++) acc[rt][ct] = (f32x16){};
        {
            f16x8 a0 = *(const f16x8*)(Wp1 + ra0);
            f16x8 a1 = *(const f16x8*)(Wp1 + ra1);
#pragma unroll 1
            for (int kt = 0; kt < 17; kt++) {
                f16x8 ca = a0, cb = a1;
                if (kt < 16) {
                    a0 = *(const f16x8*)(Wp1 + ra0 + (kt + 1) * 16);
                    a1 = *(const f16x8*)(Wp1 + ra1 + (kt + 1) * 16);
                }
                const int col = 144 + kt * 16 + hi8;
#pragma unroll
                for (int ct = 0; ct < 4; ct++) {
                    f16x8 bv = *(const f16x8*)(Xs + xb[ct] + (col ^ xk[ct]));
                    acc[0][ct] = __builtin_amdgcn_mfma_f32_32x32x16_f16(ca, bv, acc[0][ct], 0, 0, 0);
                    acc[1][ct] = __builtin_amdgcn_mfma_f32_32x32x16_f16(cb, bv, acc[1][ct], 0, 0, 0);
                }
            }
        }
        __syncthreads();   // G1 readers done before h1 overwrite

        // ===== E1: layer-1 cell update, write h1n =====
#pragma unroll
        for (int rt = 0; rt < 2; rt++)
#pragma unroll
        for (int ct = 0; ct < 4; ct++) {
#pragma unroll
            for (int rg = 0; rg < 4; rg++) {
                float gi = acc[rt][ct][4 * rg + 0];
                float gf = acc[rt][ct][4 * rg + 1];
                float gg = acc[rt][ct][4 * rg + 2];
                float go = acc[rt][ct][4 * rg + 3];
                float c = sigm(gf) * c1r[rt][rg][ct] + sigm(gi) * tanh_(gg);
                c1r[rt][rg][ct] = c;
                float h = sigm(go) * tanh_(c);
                int hid = (w << 4) + rt * 8 + 2 * rg + hi;
                Xs[xb[ct] + ((272 + hid) ^ xk[ct])] = (_Float16)h;
            }
        }
        __syncthreads();   // h1n visible

        // ===== phase C: out = Wop @ [h1n|1]^T  (waves 0..3, one 32-col batch tile each) =====
        if (w < 4) {
            const int bb  = (w << 5) + ln;
            const int xbc = bb * CS;
            const int xkc = ((bb >> 1) & 7) << 3;
            const int rc  = ln * K0 + hi8;
            f32x16 aC = {};
#pragma unroll
            for (int kt = 8; kt < 17; kt++) {
                f16x8 av = *(const f16x8*)(Wop + rc + kt * 16);
                const int col = 144 + kt * 16 + hi8;
                f16x8 bv = *(const f16x8*)(Xs + xbc + (col ^ xkc));
                aC = __builtin_amdgcn_mfma_f32_32x32x16_f16(av, bv, aC, 0, 0, 0);
            }
            float* op = out + ((size_t)(Bb + bb) * TSTEP + t) * 9;
            if (hi == 0) {
                op[0] = aC[0]; op[1] = aC[1]; op[2] = aC[2]; op[3] = aC[3]; op[8] = aC[4];
                Xs[xbc + (0 ^ xkc)] = (_Float16)aC[0];
                Xs[xbc + (1 ^ xkc)] = (_Float16)aC[1];
                Xs[xbc + (2 ^ xkc)] = (_Float16)aC[2];
                Xs[xbc + (3 ^ xkc)] = (_Float16)aC[3];
                Xs[xbc + (8 ^ xkc)] = (_Float16)aC[4];
            } else {
                op[4] = aC[0]; op[5] = aC[1]; op[6] = aC[2]; op[7] = aC[3];
                Xs[xbc + (4 ^ xkc)] = (_Float16)aC[0];
                Xs[xbc + (5 ^ xkc)] = (_Float16)aC[1];
                Xs[xbc + (6 ^ xkc)] = (_Float16)aC[2];
                Xs[xbc + (7 ^ xkc)] = (_Float16)aC[3];
            }
        }
        __syncthreads();   // prev visible for next step
    }
}

extern "C" void kernel_launch(void* const* d_in, const int* in_sizes, int n_in,
                              void* d_out, int out_size, void* d_ws, size_t ws_size,
                              hipStream_t stream) {
    const float* z     = (const float*)d_in[0];
    const int*   scen  = (const int*)d_in[1];
    // d_in[2] = seq_length (fixed 60)
    const float* emb   = (const float*)d_in[3];
    const float* Winit = (const float*)d_in[4];
    const float* binit = (const float*)d_in[5];
    const float* Wih0  = (const float*)d_in[6];
    const float* Whh0  = (const float*)d_in[7];
    const float* bih0  = (const float*)d_in[8];
    const float* bhh0  = (const float*)d_in[9];
    const float* Wih1  = (const float*)d_in[10];
    const float* Whh1  = (const float*)d_in[11];
    const float* bih1  = (const float*)d_in[12];
    const float* bhh1  = (const float*)d_in[13];
    const float* Wout  = (const float*)d_in[14];
    const float* bout  = (const float*)d_in[15];
    _Float16* ws  = (_Float16*)d_ws;
    float*    out = (float*)d_out;

    prep_kernel<<<(N0 + 255) / 256, 256, 0, stream>>>(
        Winit, binit, Wih0, Whh0, bih0, bhh0, Wih1, Whh1, bih1, bhh1, Wout, bout, ws);
    lstm_main<<<256, 512, 0, stream>>>(z, scen, emb, ws, out);
}